// Round 12
// baseline (558.897 us; speedup 1.0000x reference)
//
#include <hip/hip_runtime.h>
#include <hip/hip_fp16.h>
#include <math.h>

#define IN_C 128
#define OUT_C 128
#define BN_EPS 1e-5f
#define NODES2 64

typedef __fp16 f16x8 __attribute__((ext_vector_type(8)));
typedef __fp16 f16x2 __attribute__((ext_vector_type(2)));
typedef float f32x4 __attribute__((ext_vector_type(4)));

// ---------------- zero: deg + stats ----------------
__global__ __launch_bounds__(256) void k_zero(int* __restrict__ deg, int n,
                                              float* __restrict__ stats) {
    int idx = blockIdx.x * blockDim.x + threadIdx.x;
    int stride = gridDim.x * blockDim.x;
    for (int i = idx; i < n; i += stride) deg[i] = 0;
    if (blockIdx.x == 0 && threadIdx.x < 256) stats[threadIdx.x] = 0.0f;
}

// ---------------- histogram of dst ----------------
__global__ __launch_bounds__(256) void k_hist(const int* __restrict__ edst,
                                              int* __restrict__ deg, int E) {
    int idx = blockIdx.x * blockDim.x + threadIdx.x;
    int stride = gridDim.x * blockDim.x;
    for (int e = idx; e < E; e += stride) atomicAdd(&deg[edst[e]], 1);
}

// ---------------- exclusive scan (single block, shfl + LDS) ----------------
__global__ __launch_bounds__(1024) void k_scan(const int* __restrict__ deg,
                                               int* __restrict__ rowptr,
                                               int* __restrict__ cursor, int n) {
    __shared__ int wsum[16], woff[16], ctot;
    int t = threadIdx.x, lane = t & 63, wv = t >> 6;
    int carry = 0;
    for (int base = 0; base < n; base += 1024) {
        int i = base + t;
        int v = (i < n) ? deg[i] : 0;
        int x = v;
#pragma unroll
        for (int off = 1; off < 64; off <<= 1) {
            int u = __shfl_up(x, off, 64);
            if (lane >= off) x += u;
        }
        if (lane == 63) wsum[wv] = x;
        __syncthreads();
        if (wv == 0 && lane < 16) {
            int y = wsum[lane];
#pragma unroll
            for (int off = 1; off < 16; off <<= 1) {
                int u = __shfl_up(y, off, 16);
                if ((lane & 15) >= off) y += u;
            }
            woff[lane] = y - wsum[lane];
            if (lane == 15) ctot = y;
        }
        __syncthreads();
        int excl = carry + x + woff[wv] - v;
        if (i < n) { rowptr[i] = excl; cursor[i] = excl; }
        carry += ctot;
        __syncthreads();
    }
    if (t == 0) rowptr[n] = carry;
}

// ---------------- scatter src ids into CSR order ----------------
__global__ __launch_bounds__(256) void k_scatter(const int* __restrict__ esrc,
                                                 const int* __restrict__ edst,
                                                 int* __restrict__ cursor,
                                                 int* __restrict__ ssrc, int E) {
    int idx = blockIdx.x * blockDim.x + threadIdx.x;
    int stride = gridDim.x * blockDim.x;
    for (int e = idx; e < E; e += stride) {
        int pos = atomicAdd(&cursor[edst[e]], 1);
        ssrc[pos] = esrc[e];
    }
}

// ---------------- node precompute: A = x@(W1t-W1b)+b1, B = x@W1b (fp32) ----------------
__global__ __launch_bounds__(256) void k_node(const float* __restrict__ x,
                                              const float* __restrict__ W1,
                                              const float* __restrict__ b1,
                                              float* __restrict__ A,
                                              float* __restrict__ Bm,
                                              int n_nodes) {
    __shared__ float xs[NODES2][IN_C];   // 32 KB
    int t = threadIdx.x;
    int c = t & 127;
    bool isA = (t < 128);                 // wave-uniform
    float bias = b1[c];
    for (int base = blockIdx.x * NODES2; base < n_nodes;
         base += gridDim.x * NODES2) {
        int nn = min(NODES2, n_nodes - base);
        __syncthreads();
        for (int i = t; i < nn * IN_C; i += 256) {
            int n = i >> 7, k = i & 127;
            xs[n][k] = x[(size_t)(base + n) * IN_C + k];
        }
        __syncthreads();
        float acc[NODES2];
#pragma unroll
        for (int n = 0; n < NODES2; n++) acc[n] = 0.0f;
        for (int kh = 0; kh < IN_C; kh += 4) {
            float w[4];
#pragma unroll
            for (int j = 0; j < 4; j++) {
                float wbot = W1[(size_t)(kh + j + 128) * OUT_C + c];
                w[j] = isA ? (W1[(size_t)(kh + j) * OUT_C + c] - wbot) : wbot;
            }
#pragma unroll
            for (int n = 0; n < NODES2; n++) {
                float4 xv = *(const float4*)&xs[n][kh];
                acc[n] = fmaf(xv.x, w[0], acc[n]);
                acc[n] = fmaf(xv.y, w[1], acc[n]);
                acc[n] = fmaf(xv.z, w[2], acc[n]);
                acc[n] = fmaf(xv.w, w[3], acc[n]);
            }
        }
        float* dst = isA ? A : Bm;
        float add = isA ? bias : 0.0f;
        for (int n = 0; n < nn; n++)
            dst[(size_t)(base + n) * OUT_C + c] = acc[n] + add;
    }
}

// ---------------- grouped edge kernel: one wave per dst node ----------------
// h_row(e) = relu(A[i]+B[j_e]) @ W2 ; out[i] = max_e h_row + b2 ; fused BN stats.
// LDS rotate-swizzle: col' = (col + 8*row) & 127  (16B-aligned, conflict-free)
__global__ __launch_bounds__(256) void k_edge(const float* __restrict__ A,
                                              const float* __restrict__ Bm,
                                              const int* __restrict__ rowptr,
                                              const int* __restrict__ ssrc,
                                              const float* __restrict__ W2,
                                              const float* __restrict__ b2,
                                              float* __restrict__ out,
                                              float* __restrict__ gsum,
                                              float* __restrict__ gsumsq,
                                              int n_nodes) {
    __shared__ __fp16 w2t[128 * 128];     // 32 KB, W2^T f16 swizzled
    __shared__ __fp16 rt[4 * 16 * 128];   // 16 KB, per-wave r rows
    __shared__ float ssum[128], ssq[128];

    int t = threadIdx.x, lane = t & 63;
    int wv = t >> 6;
    int mrow = lane & 15, kgrp = lane >> 4;

    for (int idx = t; idx < 64 * 128; idx += 256) {
        int kp = idx >> 7, n = idx & 127;
        float w0 = W2[(size_t)(2 * kp) * OUT_C + n];
        float w1 = W2[(size_t)(2 * kp + 1) * OUT_C + n];
        f16x2 p = __builtin_amdgcn_cvt_pkrtz(w0, w1);
        *(f16x2*)&w2t[n * 128 + ((2 * kp + 8 * n) & 127)] = p;
    }
    if (t < 128) { ssum[t] = 0.0f; ssq[t] = 0.0f; }
    float b2r[8];
#pragma unroll
    for (int nt = 0; nt < 8; nt++) b2r[nt] = b2[nt * 16 + mrow];
    __syncthreads();

    __fp16* rtw = &rt[wv * 16 * 128];
    int gwave = blockIdx.x * 4 + wv;
    int nw = gridDim.x * 4;

    for (int i = gwave; i < n_nodes; i += nw) {
        int rbase = rowptr[i], rend = rowptr[i + 1];
        int d = rend - rbase;
        if (d == 0) {
            if (kgrp == 0) {
#pragma unroll
                for (int nt = 0; nt < 8; nt++)
                    out[(size_t)i * OUT_C + nt * 16 + mrow] = 0.0f;
            }
            continue;
        }
        float2 av = *(const float2*)&A[(size_t)i * OUT_C + 2 * lane];
        float vmax[8];
#pragma unroll
        for (int nt = 0; nt < 8; nt++) vmax[nt] = -INFINITY;

        for (int c0 = 0; c0 < d; c0 += 16) {
            int idxs = rbase + c0 + (lane & 15);
            if (idxs >= rend) idxs = rend - 1;
            int sid = ssrc[idxs];
            int nrows = min(16, d - c0);
            float2 bvs[16];
#pragma unroll
            for (int e = 0; e < 16; e++) {
                int jj = __builtin_amdgcn_readlane(sid, e);
                bvs[e] = *(const float2*)&Bm[(size_t)jj * OUT_C + 2 * lane];
            }
#pragma unroll
            for (int e = 0; e < 16; e++) {
                float r0 = fmaxf(av.x + bvs[e].x, 0.0f);
                float r1 = fmaxf(av.y + bvs[e].y, 0.0f);
                f16x2 p = __builtin_amdgcn_cvt_pkrtz(r0, r1);
                *(f16x2*)&rtw[e * 128 + ((2 * lane + 8 * e) & 127)] = p;
            }
            f32x4 acc[8];
#pragma unroll
            for (int nt = 0; nt < 8; nt++) acc[nt] = (f32x4){0.f, 0.f, 0.f, 0.f};
#pragma unroll
            for (int kk = 0; kk < 4; kk++) {
                int k0 = kk * 32 + kgrp * 8;
                f16x8 a0 = *(f16x8*)&rtw[mrow * 128 + ((k0 + 8 * mrow) & 127)];
#pragma unroll
                for (int nt = 0; nt < 8; nt++) {
                    int rr = nt * 16 + mrow;
                    f16x8 bf = *(f16x8*)&w2t[rr * 128 + ((k0 + 8 * rr) & 127)];
                    acc[nt] = __builtin_amdgcn_mfma_f32_16x16x32_f16(a0, bf, acc[nt], 0, 0, 0);
                }
            }
#pragma unroll
            for (int nt = 0; nt < 8; nt++) {
#pragma unroll
                for (int reg = 0; reg < 4; reg++) {
                    int rl = kgrp * 4 + reg;
                    if (rl < nrows) vmax[nt] = fmaxf(vmax[nt], acc[nt][reg]);
                }
            }
        }
#pragma unroll
        for (int nt = 0; nt < 8; nt++) {
            float v = vmax[nt];
            v = fmaxf(v, __shfl_xor(v, 16, 64));
            v = fmaxf(v, __shfl_xor(v, 32, 64));
            vmax[nt] = v;
        }
        if (kgrp == 0) {
#pragma unroll
            for (int nt = 0; nt < 8; nt++) {
                float v = vmax[nt] + b2r[nt];
                out[(size_t)i * OUT_C + nt * 16 + mrow] = v;
                atomicAdd(&ssum[nt * 16 + mrow], v);
                atomicAdd(&ssq[nt * 16 + mrow], v * v);
            }
        }
    }
    __syncthreads();
    if (t < 128) {
        atomicAdd(&gsum[t], ssum[t]);
        atomicAdd(&gsumsq[t], ssq[t]);
    }
}

// ---------------- finalize: scale/shift from stats ----------------
__global__ __launch_bounds__(128) void k_finalize(const float* __restrict__ gsum,
                                                  const float* __restrict__ gsumsq,
                                                  const float* __restrict__ gamma,
                                                  const float* __restrict__ beta,
                                                  float* __restrict__ scale,
                                                  float* __restrict__ shift,
                                                  int n_nodes) {
    int c = threadIdx.x;
    if (c < OUT_C) {
        float inv_n = 1.0f / (float)n_nodes;
        float mean = gsum[c] * inv_n;
        float var = fmaxf(gsumsq[c] * inv_n - mean * mean, 0.0f);
        float sc = gamma[c] * rsqrtf(var + BN_EPS);
        scale[c] = sc;
        shift[c] = beta[c] - mean * sc;
    }
}

// ---------------- normalize in place ----------------
__global__ __launch_bounds__(256) void k_norm(float* __restrict__ out,
                                              const float* __restrict__ scale,
                                              const float* __restrict__ shift,
                                              int n_vec) {
    int idx = blockIdx.x * blockDim.x + threadIdx.x;
    int stride = gridDim.x * blockDim.x;
    for (int i = idx; i < n_vec; i += stride) {
        float4 v = ((const float4*)out)[i];
        int c = (i * 4) & 127;
        float4 sc = *(const float4*)&scale[c];
        float4 sh = *(const float4*)&shift[c];
        v.x = fmaf(v.x, sc.x, sh.x);
        v.y = fmaf(v.y, sc.y, sh.y);
        v.z = fmaf(v.z, sc.z, sh.z);
        v.w = fmaf(v.w, sc.w, sh.w);
        ((float4*)out)[i] = v;
    }
}

extern "C" void kernel_launch(void* const* d_in, const int* in_sizes, int n_in,
                              void* d_out, int out_size, void* d_ws, size_t ws_size,
                              hipStream_t stream) {
    const float* x     = (const float*)d_in[0];
    const int*   ei    = (const int*)d_in[1];
    const float* W1    = (const float*)d_in[2];
    const float* b1    = (const float*)d_in[3];
    const float* W2    = (const float*)d_in[4];
    const float* b2    = (const float*)d_in[5];
    const float* gamma = (const float*)d_in[6];
    const float* beta  = (const float*)d_in[7];

    int n_nodes = in_sizes[0] / IN_C;
    int n_edges = in_sizes[1] / 2;
    const int* esrc = ei;             // edge_index[0] = source j
    const int* edst = ei + n_edges;   // edge_index[1] = target i

    float* out = (float*)d_out;
    float* A   = (float*)d_ws;
    float* Bm  = A + (size_t)n_nodes * OUT_C;
    float* stats = Bm + (size_t)n_nodes * OUT_C;
    float* gsum   = stats;
    float* gsumsq = stats + 128;
    float* scale  = stats + 256;
    float* shift  = stats + 384;
    int* deg    = (int*)(stats + 512);
    int* rowptr = deg + n_nodes;
    int* cursor = rowptr + n_nodes + 1;
    int* ssrc   = cursor + n_nodes;

    k_zero<<<256, 256, 0, stream>>>(deg, n_nodes, stats);
    k_hist<<<1024, 256, 0, stream>>>(edst, deg, n_edges);
    k_scan<<<1, 1024, 0, stream>>>(deg, rowptr, cursor, n_nodes);
    k_scatter<<<1024, 256, 0, stream>>>(esrc, edst, cursor, ssrc, n_edges);
    k_node<<<(n_nodes + NODES2 - 1) / NODES2, 256, 0, stream>>>(x, W1, b1, A, Bm, n_nodes);
    k_edge<<<768, 256, 0, stream>>>(A, Bm, rowptr, ssrc, W2, b2,
                                    out, gsum, gsumsq, n_nodes);
    k_finalize<<<1, 128, 0, stream>>>(gsum, gsumsq, gamma, beta, scale, shift, n_nodes);
    k_norm<<<2048, 256, 0, stream>>>(out, scale, shift, n_nodes * OUT_C / 4);
}

// Round 13
// 517.949 us; speedup vs baseline: 1.0791x; 1.0791x over previous
//
#include <hip/hip_runtime.h>
#include <hip/hip_fp16.h>
#include <math.h>

#define IN_C 128
#define OUT_C 128
#define BN_EPS 1e-5f
#define NODES2 64
#define SCAN_CHUNK 256

typedef __fp16 f16x8 __attribute__((ext_vector_type(8)));
typedef __fp16 f16x2 __attribute__((ext_vector_type(2)));
typedef float f32x4 __attribute__((ext_vector_type(4)));

// ---------------- zero: deg + stats ----------------
__global__ __launch_bounds__(256) void k_zero(int* __restrict__ deg, int n,
                                              float* __restrict__ stats) {
    int idx = blockIdx.x * blockDim.x + threadIdx.x;
    int stride = gridDim.x * blockDim.x;
    for (int i = idx; i < n; i += stride) deg[i] = 0;
    if (blockIdx.x == 0 && threadIdx.x < 256) stats[threadIdx.x] = 0.0f;
}

// ---------------- histogram of dst ----------------
__global__ __launch_bounds__(256) void k_hist(const int* __restrict__ edst,
                                              int* __restrict__ deg, int E) {
    int idx = blockIdx.x * blockDim.x + threadIdx.x;
    int stride = gridDim.x * blockDim.x;
    for (int e = idx; e < E; e += stride) atomicAdd(&deg[edst[e]], 1);
}

// ---------------- scan phase 1: per-block exclusive scan + block sums ----------------
__global__ __launch_bounds__(256) void k_scan1(const int* __restrict__ deg,
                                               int* __restrict__ rowptr,
                                               int* __restrict__ bsum, int n) {
    __shared__ int ws4[4];
    int t = threadIdx.x, lane = t & 63, wv = t >> 6;
    int i = blockIdx.x * SCAN_CHUNK + t;
    int v = (i < n) ? deg[i] : 0;
    int x = v;
#pragma unroll
    for (int off = 1; off < 64; off <<= 1) {
        int u = __shfl_up(x, off, 64);
        if (lane >= off) x += u;
    }
    if (lane == 63) ws4[wv] = x;
    __syncthreads();
    int woff = 0;
#pragma unroll
    for (int k = 0; k < 3; k++) if (k < wv) woff += ws4[k];
    int excl = woff + x - v;
    if (i < n) rowptr[i] = excl;
    if (t == 255) bsum[blockIdx.x] = woff + x;
}

// ---------------- scan phase 2: one-block scan of block sums (NB<=256) ----------------
__global__ __launch_bounds__(256) void k_scan2(const int* __restrict__ bsum,
                                               int* __restrict__ boff,
                                               int* __restrict__ rowptr,
                                               int NB, int n) {
    __shared__ int ws4[4];
    int t = threadIdx.x, lane = t & 63, wv = t >> 6;
    int v = (t < NB) ? bsum[t] : 0;
    int x = v;
#pragma unroll
    for (int off = 1; off < 64; off <<= 1) {
        int u = __shfl_up(x, off, 64);
        if (lane >= off) x += u;
    }
    if (lane == 63) ws4[wv] = x;
    __syncthreads();
    int woff = 0;
#pragma unroll
    for (int k = 0; k < 3; k++) if (k < wv) woff += ws4[k];
    int excl = woff + x - v;
    if (t < NB) boff[t] = excl;
    if (t == NB - 1) rowptr[n] = excl + v;
}

// ---------------- scan phase 3: add block offsets, init cursor ----------------
__global__ __launch_bounds__(256) void k_scan3(int* __restrict__ rowptr,
                                               const int* __restrict__ boff,
                                               int* __restrict__ cursor, int n) {
    int i = blockIdx.x * SCAN_CHUNK + threadIdx.x;
    if (i < n) {
        int r = rowptr[i] + boff[blockIdx.x];
        rowptr[i] = r;
        cursor[i] = r;
    }
}

// ---------------- scatter src ids into CSR order ----------------
__global__ __launch_bounds__(256) void k_scatter(const int* __restrict__ esrc,
                                                 const int* __restrict__ edst,
                                                 int* __restrict__ cursor,
                                                 int* __restrict__ ssrc, int E) {
    int idx = blockIdx.x * blockDim.x + threadIdx.x;
    int stride = gridDim.x * blockDim.x;
    for (int e = idx; e < E; e += stride) {
        int pos = atomicAdd(&cursor[edst[e]], 1);
        ssrc[pos] = esrc[e];
    }
}

// ---------------- node precompute: A = x@(W1t-W1b)+b1 (f32), B = x@W1b (f16) ----------------
__global__ __launch_bounds__(256) void k_node(const float* __restrict__ x,
                                              const float* __restrict__ W1,
                                              const float* __restrict__ b1,
                                              float* __restrict__ A,
                                              __fp16* __restrict__ Bm,
                                              int n_nodes) {
    __shared__ float xs[NODES2][IN_C];   // 32 KB
    int t = threadIdx.x;
    int c = t & 127;
    bool isA = (t < 128);                 // wave-uniform
    float bias = b1[c];
    for (int base = blockIdx.x * NODES2; base < n_nodes;
         base += gridDim.x * NODES2) {
        int nn = min(NODES2, n_nodes - base);
        __syncthreads();
        for (int i = t; i < nn * IN_C; i += 256) {
            int n = i >> 7, k = i & 127;
            xs[n][k] = x[(size_t)(base + n) * IN_C + k];
        }
        __syncthreads();
        float acc[NODES2];
#pragma unroll
        for (int n = 0; n < NODES2; n++) acc[n] = 0.0f;
        for (int kh = 0; kh < IN_C; kh += 4) {
            float w[4];
#pragma unroll
            for (int j = 0; j < 4; j++) {
                float wbot = W1[(size_t)(kh + j + 128) * OUT_C + c];
                w[j] = isA ? (W1[(size_t)(kh + j) * OUT_C + c] - wbot) : wbot;
            }
#pragma unroll
            for (int n = 0; n < NODES2; n++) {
                float4 xv = *(const float4*)&xs[n][kh];
                acc[n] = fmaf(xv.x, w[0], acc[n]);
                acc[n] = fmaf(xv.y, w[1], acc[n]);
                acc[n] = fmaf(xv.z, w[2], acc[n]);
                acc[n] = fmaf(xv.w, w[3], acc[n]);
            }
        }
        if (isA) {
            for (int n = 0; n < nn; n++)
                A[(size_t)(base + n) * OUT_C + c] = acc[n] + bias;
        } else {
            for (int n = 0; n < nn; n++)
                Bm[(size_t)(base + n) * OUT_C + c] = (__fp16)acc[n];
        }
    }
}

// ---------------- grouped edge kernel: one wave per dst node ----------------
// h_row(e) = relu(A[i]+B[j_e]) @ W2 ; out[i] = max_e h_row + b2 ; fused BN stats.
// LDS rotate-swizzle: col' = (col + 8*row) & 127  (16B-aligned)
__global__ __launch_bounds__(256) void k_edge(const float* __restrict__ A,
                                              const __fp16* __restrict__ Bm,
                                              const int* __restrict__ rowptr,
                                              const int* __restrict__ ssrc,
                                              const float* __restrict__ W2,
                                              const float* __restrict__ b2,
                                              float* __restrict__ out,
                                              float* __restrict__ gsum,
                                              float* __restrict__ gsumsq,
                                              int n_nodes) {
    __shared__ __fp16 w2t[128 * 128];     // 32 KB, W2^T f16 swizzled
    __shared__ __fp16 rt[4 * 16 * 128];   // 16 KB, per-wave r rows
    __shared__ float ssum[128], ssq[128];

    int t = threadIdx.x, lane = t & 63;
    int wv = t >> 6;
    int mrow = lane & 15, kgrp = lane >> 4;

    for (int idx = t; idx < 64 * 128; idx += 256) {
        int kp = idx >> 7, n = idx & 127;
        float w0 = W2[(size_t)(2 * kp) * OUT_C + n];
        float w1 = W2[(size_t)(2 * kp + 1) * OUT_C + n];
        f16x2 p = __builtin_amdgcn_cvt_pkrtz(w0, w1);
        *(f16x2*)&w2t[n * 128 + ((2 * kp + 8 * n) & 127)] = p;
    }
    if (t < 128) { ssum[t] = 0.0f; ssq[t] = 0.0f; }
    float b2r[8];
#pragma unroll
    for (int nt = 0; nt < 8; nt++) b2r[nt] = b2[nt * 16 + mrow];
    __syncthreads();

    __fp16* rtw = &rt[wv * 16 * 128];
    int gwave = blockIdx.x * 4 + wv;
    int nw = gridDim.x * 4;

    for (int i = gwave; i < n_nodes; i += nw) {
        int rbase = rowptr[i], rend = rowptr[i + 1];
        int d = rend - rbase;
        if (d == 0) {
            if (kgrp == 0) {
#pragma unroll
                for (int nt = 0; nt < 8; nt++)
                    out[(size_t)i * OUT_C + nt * 16 + mrow] = 0.0f;
            }
            continue;
        }
        float2 av = *(const float2*)&A[(size_t)i * OUT_C + 2 * lane];
        float vmax[8];
#pragma unroll
        for (int nt = 0; nt < 8; nt++) vmax[nt] = -INFINITY;

        for (int c0 = 0; c0 < d; c0 += 16) {
            int idxs = rbase + c0 + (lane & 15);
            if (idxs >= rend) idxs = rend - 1;
            int sid = ssrc[idxs];
            int nrows = min(16, d - c0);
            f16x2 bvs[16];
#pragma unroll
            for (int e = 0; e < 16; e++) {
                int jj = __builtin_amdgcn_readlane(sid, e);
                bvs[e] = *(const f16x2*)&Bm[(size_t)jj * OUT_C + 2 * lane];
            }
#pragma unroll
            for (int e = 0; e < 16; e++) {
                float r0 = fmaxf(av.x + (float)bvs[e].x, 0.0f);
                float r1 = fmaxf(av.y + (float)bvs[e].y, 0.0f);
                f16x2 p = __builtin_amdgcn_cvt_pkrtz(r0, r1);
                *(f16x2*)&rtw[e * 128 + ((2 * lane + 8 * e) & 127)] = p;
            }
            f32x4 acc[8];
#pragma unroll
            for (int nt = 0; nt < 8; nt++) acc[nt] = (f32x4){0.f, 0.f, 0.f, 0.f};
#pragma unroll
            for (int kk = 0; kk < 4; kk++) {
                int k0 = kk * 32 + kgrp * 8;
                f16x8 a0 = *(f16x8*)&rtw[mrow * 128 + ((k0 + 8 * mrow) & 127)];
#pragma unroll
                for (int nt = 0; nt < 8; nt++) {
                    int rr = nt * 16 + mrow;
                    f16x8 bf = *(f16x8*)&w2t[rr * 128 + ((k0 + 8 * rr) & 127)];
                    acc[nt] = __builtin_amdgcn_mfma_f32_16x16x32_f16(a0, bf, acc[nt], 0, 0, 0);
                }
            }
#pragma unroll
            for (int nt = 0; nt < 8; nt++) {
#pragma unroll
                for (int reg = 0; reg < 4; reg++) {
                    int rl = kgrp * 4 + reg;
                    if (rl < nrows) vmax[nt] = fmaxf(vmax[nt], acc[nt][reg]);
                }
            }
        }
#pragma unroll
        for (int nt = 0; nt < 8; nt++) {
            float v = vmax[nt];
            v = fmaxf(v, __shfl_xor(v, 16, 64));
            v = fmaxf(v, __shfl_xor(v, 32, 64));
            vmax[nt] = v;
        }
        if (kgrp == 0) {
#pragma unroll
            for (int nt = 0; nt < 8; nt++) {
                float v = vmax[nt] + b2r[nt];
                out[(size_t)i * OUT_C + nt * 16 + mrow] = v;
                atomicAdd(&ssum[nt * 16 + mrow], v);
                atomicAdd(&ssq[nt * 16 + mrow], v * v);
            }
        }
    }
    __syncthreads();
    if (t < 128) {
        atomicAdd(&gsum[t], ssum[t]);
        atomicAdd(&gsumsq[t], ssq[t]);
    }
}

// ---------------- finalize: scale/shift from stats ----------------
__global__ __launch_bounds__(128) void k_finalize(const float* __restrict__ gsum,
                                                  const float* __restrict__ gsumsq,
                                                  const float* __restrict__ gamma,
                                                  const float* __restrict__ beta,
                                                  float* __restrict__ scale,
                                                  float* __restrict__ shift,
                                                  int n_nodes) {
    int c = threadIdx.x;
    if (c < OUT_C) {
        float inv_n = 1.0f / (float)n_nodes;
        float mean = gsum[c] * inv_n;
        float var = fmaxf(gsumsq[c] * inv_n - mean * mean, 0.0f);
        float sc = gamma[c] * rsqrtf(var + BN_EPS);
        scale[c] = sc;
        shift[c] = beta[c] - mean * sc;
    }
}

// ---------------- normalize in place ----------------
__global__ __launch_bounds__(256) void k_norm(float* __restrict__ out,
                                              const float* __restrict__ scale,
                                              const float* __restrict__ shift,
                                              int n_vec) {
    int idx = blockIdx.x * blockDim.x + threadIdx.x;
    int stride = gridDim.x * blockDim.x;
    for (int i = idx; i < n_vec; i += stride) {
        float4 v = ((const float4*)out)[i];
        int c = (i * 4) & 127;
        float4 sc = *(const float4*)&scale[c];
        float4 sh = *(const float4*)&shift[c];
        v.x = fmaf(v.x, sc.x, sh.x);
        v.y = fmaf(v.y, sc.y, sh.y);
        v.z = fmaf(v.z, sc.z, sh.z);
        v.w = fmaf(v.w, sc.w, sh.w);
        ((float4*)out)[i] = v;
    }
}

extern "C" void kernel_launch(void* const* d_in, const int* in_sizes, int n_in,
                              void* d_out, int out_size, void* d_ws, size_t ws_size,
                              hipStream_t stream) {
    const float* x     = (const float*)d_in[0];
    const int*   ei    = (const int*)d_in[1];
    const float* W1    = (const float*)d_in[2];
    const float* b1    = (const float*)d_in[3];
    const float* W2    = (const float*)d_in[4];
    const float* b2    = (const float*)d_in[5];
    const float* gamma = (const float*)d_in[6];
    const float* beta  = (const float*)d_in[7];

    int n_nodes = in_sizes[0] / IN_C;
    int n_edges = in_sizes[1] / 2;
    const int* esrc = ei;             // edge_index[0] = source j
    const int* edst = ei + n_edges;   // edge_index[1] = target i

    float* out = (float*)d_out;
    float* A   = (float*)d_ws;
    __fp16* Bm = (__fp16*)(A + (size_t)n_nodes * OUT_C);
    float* stats = (float*)(Bm + (size_t)n_nodes * OUT_C);
    float* gsum   = stats;
    float* gsumsq = stats + 128;
    float* scale  = stats + 256;
    float* shift  = stats + 384;
    int* deg    = (int*)(stats + 512);
    int* rowptr = deg + n_nodes;
    int* cursor = rowptr + n_nodes + 1;
    int* ssrc   = cursor + n_nodes;
    int* bsum   = ssrc + n_edges;
    int NB = (n_nodes + SCAN_CHUNK - 1) / SCAN_CHUNK;   // 196 for n=50000 (<=256)
    int* boff   = bsum + NB;

    k_zero<<<256, 256, 0, stream>>>(deg, n_nodes, stats);
    k_hist<<<1024, 256, 0, stream>>>(edst, deg, n_edges);
    k_scan1<<<NB, 256, 0, stream>>>(deg, rowptr, bsum, n_nodes);
    k_scan2<<<1, 256, 0, stream>>>(bsum, boff, rowptr, NB, n_nodes);
    k_scan3<<<NB, 256, 0, stream>>>(rowptr, boff, cursor, n_nodes);
    k_scatter<<<1024, 256, 0, stream>>>(esrc, edst, cursor, ssrc, n_edges);
    k_node<<<(n_nodes + NODES2 - 1) / NODES2, 256, 0, stream>>>(x, W1, b1, A, Bm, n_nodes);
    k_edge<<<768, 256, 0, stream>>>(A, Bm, rowptr, ssrc, W2, b2,
                                    out, gsum, gsumsq, n_nodes);
    k_finalize<<<1, 128, 0, stream>>>(gsum, gsumsq, gamma, beta, scale, shift, n_nodes);
    k_norm<<<2048, 256, 0, stream>>>(out, scale, shift, n_nodes * OUT_C / 4);
}